// Round 2
// baseline (190.366 us; speedup 1.0000x reference)
//
#include <hip/hip_runtime.h>

#define N_INNER 2000
#define N_LEAF  10000
#define N_DOC   128
#define AM_CHUNKS 50
#define AM_ROWS   40        // 50*40 = 2000 rows
#define DW   64             // dist column-chunk width
#define DCH  188            // ceil(12000/64)

// ---------------- Kernel 1: per-chunk column argmax of param ----------------
// grid (10, 50), block 256. Each thread owns 4 consecutive columns (float4).
__global__ __launch_bounds__(256) void k_amax_part(const float* __restrict__ param,
                                                   float* __restrict__ pmax,
                                                   unsigned* __restrict__ pidx) {
    int j0 = (blockIdx.x * 256 + threadIdx.x) * 4;
    if (j0 >= N_LEAF) return;
    int r0 = blockIdx.y * AM_ROWS;
    float b0 = -1e30f, b1 = -1e30f, b2 = -1e30f, b3 = -1e30f;
    unsigned i0 = 0, i1 = 0, i2 = 0, i3 = 0;
    const float* p = param + (size_t)r0 * N_LEAF + j0;
    #pragma unroll 8
    for (int r = 0; r < AM_ROWS; ++r) {
        float4 v = *(const float4*)p;
        p += N_LEAF;
        unsigned row = (unsigned)(r0 + r);
        if (v.x > b0) { b0 = v.x; i0 = row; }
        if (v.y > b1) { b1 = v.y; i1 = row; }
        if (v.z > b2) { b2 = v.z; i2 = row; }
        if (v.w > b3) { b3 = v.w; i3 = row; }
    }
    size_t o = (size_t)blockIdx.y * N_LEAF + j0;
    *(float4*)(pmax + o) = make_float4(b0, b1, b2, b3);
    *(uint4*)(pidx + o)  = make_uint4(i0, i1, i2, i3);
}

// ---------------- Kernel 2: reduce chunks -> argmax node per leaf ----------------
__global__ __launch_bounds__(256) void k_amax_reduce(const float* __restrict__ pmax,
                                                     const unsigned* __restrict__ pidx,
                                                     int* __restrict__ amax) {
    int j = blockIdx.x * 256 + threadIdx.x;
    if (j >= N_LEAF) return;
    float best = pmax[j];
    unsigned bi = pidx[j];
    #pragma unroll 7
    for (int c = 1; c < AM_CHUNKS; ++c) {
        float v = pmax[(size_t)c * N_LEAF + j];
        if (v > best) { best = v; bi = pidx[(size_t)c * N_LEAF + j]; }
    }
    amax[j] = (int)bi;
}

// ---------------- Kernel 3: per-doc w accumulation (LDS) + prefix scan + S ----------------
// grid (128), block 256. Pex[d][k] = sum w[d][0..k-1], k in [0,2000].
// S[d] = sum_k (depth_k + 2) * w[d][k]  ( = sum(proj row) + sum(mass row) )
__global__ __launch_bounds__(256) void k_wscan(const int* __restrict__ amax,
                                               const float* __restrict__ mass,
                                               float* __restrict__ Pex,
                                               float* __restrict__ S) {
    __shared__ float wl[N_INNER];
    __shared__ float sm[256];
    __shared__ float sm2[256];
    int d = blockIdx.x, t = threadIdx.x;
    for (int k = t; k < N_INNER; k += 256) wl[k] = 0.f;
    __syncthreads();
    const float* md = mass + (size_t)d * N_LEAF;
    for (int j = t; j < N_LEAF; j += 256) atomicAdd(&wl[amax[j]], md[j]);
    __syncthreads();
    float loc[8];
    float s = 0.f, s2 = 0.f;
    #pragma unroll
    for (int k = 0; k < 8; ++k) {
        int idx = t * 8 + k;
        float v = (idx < N_INNER) ? wl[idx] : 0.f;
        loc[k] = s;              // thread-local exclusive prefix
        s += v;
        float dep = (float)((idx >= 1) + (idx >= 6) + (idx >= 31) + (idx >= 156) + (idx >= 781) + 2);
        s2 += dep * v;
    }
    sm[t] = s; sm2[t] = s2;
    __syncthreads();
    // Hillis-Steele inclusive scan over 256 thread-sums
    for (int off = 1; off < 256; off <<= 1) {
        float v = (t >= off) ? sm[t - off] : 0.f;
        __syncthreads();
        sm[t] += v;
        __syncthreads();
    }
    float base = sm[t] - s;      // exclusive prefix of this thread's segment
    float* Pd = Pex + (size_t)d * (N_INNER + 1);
    #pragma unroll
    for (int k = 0; k < 8; ++k) {
        int idx = t * 8 + k;
        if (idx <= N_INNER) Pd[idx] = base + loc[k];
    }
    // reduce s2 -> S[d]
    for (int off = 128; off > 0; off >>= 1) {
        if (t < off) sm2[t] += sm2[t + off];
        __syncthreads();
    }
    if (t == 0) S[d] = sm2[0];
}

// ---------------- Kernel 4: proj[d][i] via <=6 contiguous level-range sums ----------------
__global__ __launch_bounds__(256) void k_proj(const float* __restrict__ Pex,
                                              float* __restrict__ proj) {
    int id = blockIdx.x * 256 + threadIdx.x;   // exactly 256000
    int d = id / N_INNER;
    int i = id - d * N_INNER;
    const float* Pd = Pex + (size_t)d * (N_INNER + 1);
    float sum = 0.f;
    int s = i, e = i;
    while (s < N_INNER) {
        int ee = (e < N_INNER - 1) ? e : (N_INNER - 1);
        sum += Pd[ee + 1] - Pd[s];
        s = 5 * s + 1;
        e = 5 * e + 5;
    }
    proj[(size_t)d * N_INNER + i] = sum;
}

// ---------------- Kernel 5: pairwise sum-of-min over feat = [proj | mass] ----------------
// grid (188, 2), block 256. Block = (column chunk of 64, j-half of 64 docs).
// Pair tile 128(i) x 64(j); per thread 8x4 pairs; LDS 192 rows x 64 cols, XOR-swizzled.
__global__ __launch_bounds__(256) void k_dist(const float* __restrict__ proj,
                                              const float* __restrict__ mass,
                                              float* __restrict__ partial) {
    __shared__ float lds[192 * DW];
    int t = threadIdx.x;
    int ch = blockIdx.x, jt = blockIdx.y;
    int c0 = ch * DW;
    int jbase = jt * 64;
    // stage 192 rows x 64 cols (i-rows 0..127 = docs 0..127; j-rows 128..191 = docs jbase..jbase+63)
    #pragma unroll
    for (int k = 0; k < 12; ++k) {
        int f = t + k * 256;          // 0..3071 float4 slots
        int row = f >> 4, g = f & 15;
        int doc = (row < 128) ? row : (jbase + (row - 128));
        int col = c0 + g * 4;
        float4 v = make_float4(0.f, 0.f, 0.f, 0.f);
        if (col < N_INNER)            v = *(const float4*)(proj + (size_t)doc * N_INNER + col);
        else if (col < N_INNER + N_LEAF) v = *(const float4*)(mass + (size_t)doc * N_LEAF + (col - N_INNER));
        int gg = g ^ ((row >> 3) & 7);
        *(float4*)(&lds[row * DW + gg * 4]) = v;
    }
    __syncthreads();
    int tx = t & 15, ty = t >> 4;
    int ib = ty * 8;                  // 8 i-rows
    int jb = 128 + tx * 4;            // 4 j-rows (lds row index)
    int swi = ty & 7;                 // (row>>3)&7 constant over r for i-rows
    int swj = (tx >> 1) & 7;          // constant over jr for j-rows
    float acc[8][4];
    #pragma unroll
    for (int r = 0; r < 8; ++r)
        #pragma unroll
        for (int q = 0; q < 4; ++q) acc[r][q] = 0.f;
    #pragma unroll 4
    for (int cg = 0; cg < 16; ++cg) {
        float4 bv[4];
        #pragma unroll
        for (int jr = 0; jr < 4; ++jr)
            bv[jr] = *(const float4*)(&lds[(jb + jr) * DW + ((cg ^ swj) << 2)]);
        #pragma unroll
        for (int r = 0; r < 8; ++r) {
            float4 av = *(const float4*)(&lds[(ib + r) * DW + ((cg ^ swi) << 2)]);
            #pragma unroll
            for (int q = 0; q < 4; ++q) {
                acc[r][q] += (fminf(av.x, bv[q].x) + fminf(av.y, bv[q].y))
                           + (fminf(av.z, bv[q].z) + fminf(av.w, bv[q].w));
            }
        }
    }
    float* pp = partial + (size_t)ch * 16384 + jbase;
    #pragma unroll
    for (int r = 0; r < 8; ++r) {
        *(float4*)(pp + (size_t)(ib + r) * 128 + tx * 4) =
            make_float4(acc[r][0], acc[r][1], acc[r][2], acc[r][3]);
    }
}

// ---------------- Kernel 6: reduce chunks, apply out = S_i + S_j - 2*summin ----------------
__global__ __launch_bounds__(256) void k_out(const float* __restrict__ partial,
                                             const float* __restrict__ S,
                                             float* __restrict__ out) {
    int p = blockIdx.x * 256 + threadIdx.x;   // 64 blocks * 256 = 16384
    float s0 = 0.f, s1 = 0.f, s2 = 0.f, s3 = 0.f;
    #pragma unroll 8
    for (int c = 0; c < DCH; c += 4) {
        s0 += partial[(size_t)(c + 0) * 16384 + p];
        s1 += partial[(size_t)(c + 1) * 16384 + p];
        s2 += partial[(size_t)(c + 2) * 16384 + p];
        s3 += partial[(size_t)(c + 3) * 16384 + p];
    }
    int i = p >> 7, j = p & 127;
    out[p] = S[i] + S[j] - 2.f * ((s0 + s1) + (s2 + s3));
}

extern "C" void kernel_launch(void* const* d_in, const int* in_sizes, int n_in,
                              void* d_out, int out_size, void* d_ws, size_t ws_size,
                              hipStream_t stream) {
    const float* mass  = (const float*)d_in[0];   // 128 x 10000
    const float* param = (const float*)d_in[1];   // 2000 x 10000
    float* out = (float*)d_out;                   // 128 x 128
    char* ws = (char*)d_ws;

    float*    pmax    = (float*)(ws + 0);              // 50*10000*4 = 2,000,000
    unsigned* pidx    = (unsigned*)(ws + 2000000);     // 2,000,000
    int*      amax    = (int*)(ws + 4000000);          // 40,000
    float*    Pex     = (float*)(ws + 4040000);        // 128*2001*4 = 1,024,512
    float*    proj    = (float*)(ws + 5064512);        // 128*2000*4 = 1,024,000
    float*    S       = (float*)(ws + 6088512);        // 512
    float*    partial = (float*)(ws + 6089024);        // 188*16384*4 = 12,320,768

    k_amax_part  <<<dim3(10, AM_CHUNKS), 256, 0, stream>>>(param, pmax, pidx);
    k_amax_reduce<<<dim3(40),            256, 0, stream>>>(pmax, pidx, amax);
    k_wscan      <<<dim3(N_DOC),         256, 0, stream>>>(amax, mass, Pex, S);
    k_proj       <<<dim3(1000),          256, 0, stream>>>(Pex, proj);
    k_dist       <<<dim3(DCH, 2),        256, 0, stream>>>(proj, mass, partial);
    k_out        <<<dim3(64),            256, 0, stream>>>(partial, S, out);
}

// Round 3
// 175.388 us; speedup vs baseline: 1.0854x; 1.0854x over previous
//
#include <hip/hip_runtime.h>

#define N_INNER 2000
#define N_LEAF  10000
#define N_DOC   128
#define AM_CHUNKS 50
#define AM_ROWS   40        // 50*40 = 2000 rows
#define DW   64             // dist column-chunk width
#define DCH  188            // ceil(12000/64)

__device__ __forceinline__ unsigned enc_f32(float f) {
    unsigned u = __float_as_uint(f);
    return (u & 0x80000000u) ? ~u : (u | 0x80000000u);   // monotone float->uint
}

// ---------------- Kernel 1: column argmax of param via packed u64 atomicMax ----------------
// grid (10, 50), block 256. Each thread owns 4 consecutive columns (float4).
// packed[j] = (enc(max) << 32) | row. packed must be zeroed first (enc of any finite > 0).
__global__ __launch_bounds__(256) void k_amax(const float* __restrict__ param,
                                              unsigned long long* __restrict__ packed) {
    int j0 = (blockIdx.x * 256 + threadIdx.x) * 4;
    if (j0 >= N_LEAF) return;
    int r0 = blockIdx.y * AM_ROWS;
    float b0 = -1e30f, b1 = -1e30f, b2 = -1e30f, b3 = -1e30f;
    unsigned i0 = 0, i1 = 0, i2 = 0, i3 = 0;
    const float* p = param + (size_t)r0 * N_LEAF + j0;
    #pragma unroll 8
    for (int r = 0; r < AM_ROWS; ++r) {
        float4 v = *(const float4*)p;
        p += N_LEAF;
        unsigned row = (unsigned)(r0 + r);
        if (v.x > b0) { b0 = v.x; i0 = row; }
        if (v.y > b1) { b1 = v.y; i1 = row; }
        if (v.z > b2) { b2 = v.z; i2 = row; }
        if (v.w > b3) { b3 = v.w; i3 = row; }
    }
    atomicMax(&packed[j0 + 0], ((unsigned long long)enc_f32(b0) << 32) | i0);
    atomicMax(&packed[j0 + 1], ((unsigned long long)enc_f32(b1) << 32) | i1);
    atomicMax(&packed[j0 + 2], ((unsigned long long)enc_f32(b2) << 32) | i2);
    atomicMax(&packed[j0 + 3], ((unsigned long long)enc_f32(b3) << 32) | i3);
}

// ---------------- Kernel 2: per-doc w accumulation + wave scan + S + proj (fused) ----------
// grid (128), block 256. Pex kept in LDS; proj written to global for k_dist.
// S[d] = sum_k (depth_k + 2) * w[d][k]
__global__ __launch_bounds__(256) void k_wscan_proj(const unsigned long long* __restrict__ packed,
                                                    const float* __restrict__ mass,
                                                    float* __restrict__ proj,
                                                    float* __restrict__ S) {
    __shared__ float wl[N_INNER];
    __shared__ float Px[N_INNER + 1];
    __shared__ float wsum[4], wsum2[4];
    int d = blockIdx.x, t = threadIdx.x;
    for (int k = t; k < N_INNER; k += 256) wl[k] = 0.f;
    __syncthreads();
    const float* md = mass + (size_t)d * N_LEAF;
    const unsigned* pw = (const unsigned*)packed;   // low word = argmax row (LE)
    #pragma unroll
    for (int it = 0; it < 10; ++it) {
        int j0 = (t + it * 256) * 4;
        if (j0 < N_LEAF) {
            float4 v = *(const float4*)(md + j0);
            atomicAdd(&wl[pw[2 * (j0 + 0)]], v.x);
            atomicAdd(&wl[pw[2 * (j0 + 1)]], v.y);
            atomicAdd(&wl[pw[2 * (j0 + 2)]], v.z);
            atomicAdd(&wl[pw[2 * (j0 + 3)]], v.w);
        }
    }
    __syncthreads();
    // thread-local segment [t*8, t*8+8)
    float loc[8];
    float s = 0.f, s2 = 0.f;
    #pragma unroll
    for (int k = 0; k < 8; ++k) {
        int idx = t * 8 + k;
        float v = (idx < N_INNER) ? wl[idx] : 0.f;
        loc[k] = s;
        s += v;
        float dep = (float)((idx >= 1) + (idx >= 6) + (idx >= 31) + (idx >= 156) + (idx >= 781) + 2);
        s2 += dep * v;
    }
    int lane = t & 63, w = t >> 6;
    // wave64 inclusive scan of thread sums
    float ws = s;
    #pragma unroll
    for (int off = 1; off < 64; off <<= 1) {
        float o = __shfl_up(ws, off, 64);
        if (lane >= off) ws += o;
    }
    // wave64 reduce of s2
    float r2 = s2;
    #pragma unroll
    for (int off = 32; off > 0; off >>= 1) r2 += __shfl_down(r2, off, 64);
    if (lane == 63) wsum[w] = ws;
    if (lane == 0)  wsum2[w] = r2;
    __syncthreads();
    float base = ws - s;                 // exclusive prefix within wave
    for (int q = 0; q < w; ++q) base += wsum[q];
    #pragma unroll
    for (int k = 0; k < 8; ++k) {
        int idx = t * 8 + k;
        if (idx <= N_INNER) Px[idx] = base + loc[k];
    }
    if (t == 0) S[d] = (wsum2[0] + wsum2[1]) + (wsum2[2] + wsum2[3]);
    __syncthreads();
    // proj[d][i]: <=6 contiguous level-range sums out of LDS prefix
    float* pd = proj + (size_t)d * N_INNER;
    #pragma unroll
    for (int k = 0; k < 8; ++k) {
        int i = t + k * 256;
        if (i < N_INNER) {
            float sum = 0.f;
            int s0 = i, e0 = i;
            while (s0 < N_INNER) {
                int ee = (e0 < N_INNER - 1) ? e0 : (N_INNER - 1);
                sum += Px[ee + 1] - Px[s0];
                s0 = 5 * s0 + 1;
                e0 = 5 * e0 + 5;
            }
            pd[i] = sum;
        }
    }
}

// ---------------- Kernel 3: pairwise sum-of-min over feat = [proj | mass] ----------------
// grid (188, 2), block 256. Pair tile 128(i) x 64(j); per thread 8x4; XOR-swizzled LDS.
__global__ __launch_bounds__(256) void k_dist(const float* __restrict__ proj,
                                              const float* __restrict__ mass,
                                              float* __restrict__ partial) {
    __shared__ float lds[192 * DW];
    int t = threadIdx.x;
    int ch = blockIdx.x, jt = blockIdx.y;
    int c0 = ch * DW;
    int jbase = jt * 64;
    #pragma unroll
    for (int k = 0; k < 12; ++k) {
        int f = t + k * 256;          // 0..3071 float4 slots
        int row = f >> 4, g = f & 15;
        int doc = (row < 128) ? row : (jbase + (row - 128));
        int col = c0 + g * 4;
        float4 v = make_float4(0.f, 0.f, 0.f, 0.f);
        if (col < N_INNER)               v = *(const float4*)(proj + (size_t)doc * N_INNER + col);
        else if (col < N_INNER + N_LEAF) v = *(const float4*)(mass + (size_t)doc * N_LEAF + (col - N_INNER));
        int gg = g ^ ((row >> 3) & 7);
        *(float4*)(&lds[row * DW + gg * 4]) = v;
    }
    __syncthreads();
    int tx = t & 15, ty = t >> 4;
    int ib = ty * 8;
    int jb = 128 + tx * 4;
    int swi = ty & 7;
    int swj = (tx >> 1) & 7;
    float acc[8][4];
    #pragma unroll
    for (int r = 0; r < 8; ++r)
        #pragma unroll
        for (int q = 0; q < 4; ++q) acc[r][q] = 0.f;
    #pragma unroll 4
    for (int cg = 0; cg < 16; ++cg) {
        float4 bv[4];
        #pragma unroll
        for (int jr = 0; jr < 4; ++jr)
            bv[jr] = *(const float4*)(&lds[(jb + jr) * DW + ((cg ^ swj) << 2)]);
        #pragma unroll
        for (int r = 0; r < 8; ++r) {
            float4 av = *(const float4*)(&lds[(ib + r) * DW + ((cg ^ swi) << 2)]);
            #pragma unroll
            for (int q = 0; q < 4; ++q) {
                acc[r][q] += (fminf(av.x, bv[q].x) + fminf(av.y, bv[q].y))
                           + (fminf(av.z, bv[q].z) + fminf(av.w, bv[q].w));
            }
        }
    }
    float* pp = partial + (size_t)ch * 16384 + jbase;
    #pragma unroll
    for (int r = 0; r < 8; ++r) {
        *(float4*)(pp + (size_t)(ib + r) * 128 + tx * 4) =
            make_float4(acc[r][0], acc[r][1], acc[r][2], acc[r][3]);
    }
}

// ---------------- Kernel 4: reduce chunks, out = S_i + S_j - 2*summin ----------------
__global__ __launch_bounds__(256) void k_out(const float* __restrict__ partial,
                                             const float* __restrict__ S,
                                             float* __restrict__ out) {
    int p = blockIdx.x * 256 + threadIdx.x;   // 64 blocks * 256 = 16384
    float s0 = 0.f, s1 = 0.f, s2 = 0.f, s3 = 0.f;
    #pragma unroll 8
    for (int c = 0; c < DCH; c += 4) {
        s0 += partial[(size_t)(c + 0) * 16384 + p];
        s1 += partial[(size_t)(c + 1) * 16384 + p];
        s2 += partial[(size_t)(c + 2) * 16384 + p];
        s3 += partial[(size_t)(c + 3) * 16384 + p];
    }
    int i = p >> 7, j = p & 127;
    out[p] = S[i] + S[j] - 2.f * ((s0 + s1) + (s2 + s3));
}

extern "C" void kernel_launch(void* const* d_in, const int* in_sizes, int n_in,
                              void* d_out, int out_size, void* d_ws, size_t ws_size,
                              hipStream_t stream) {
    const float* mass  = (const float*)d_in[0];   // 128 x 10000
    const float* param = (const float*)d_in[1];   // 2000 x 10000
    float* out = (float*)d_out;                   // 128 x 128
    char* ws = (char*)d_ws;

    unsigned long long* packed = (unsigned long long*)(ws + 0);  // 10000*8 = 80,000
    float* proj    = (float*)(ws + 80000);                       // 128*2000*4 = 1,024,000
    float* S       = (float*)(ws + 1104000);                     // 512
    float* partial = (float*)(ws + 1104512);                     // 188*16384*4 = 12,320,768

    hipMemsetAsync(packed, 0, N_LEAF * sizeof(unsigned long long), stream);
    k_amax       <<<dim3(10, AM_CHUNKS), 256, 0, stream>>>(param, packed);
    k_wscan_proj <<<dim3(N_DOC),         256, 0, stream>>>(packed, mass, proj, S);
    k_dist       <<<dim3(DCH, 2),        256, 0, stream>>>(proj, mass, partial);
    k_out        <<<dim3(64),            256, 0, stream>>>(partial, S, out);
}